// Round 1
// baseline (1248.730 us; speedup 1.0000x reference)
//
#include <hip/hip_runtime.h>
#include <math.h>

// Problem constants (B=1)
#define L_Q     2048
#define KV_PREV 2048
#define KV_TOT  4096
#define DIM     2048
#define D_KV    512
#define NH      16
#define DH      32
#define HDh     512   // NH*DH

// inv_freq[j] = 10000^(-j/16) = 10^(-j/4), precomputed in double.
__device__ __constant__ double c_invfreq[16] = {
    1.0,
    0.5623413251903491,
    0.31622776601683794,
    0.17782794100389228,
    0.1,
    0.05623413251903491,
    0.03162277660168379,
    0.017782794100389228,
    0.01,
    0.005623413251903491,
    0.0031622776601683794,
    0.0017782794100389228,
    0.001,
    0.0005623413251903491,
    0.00031622776601683794,
    0.00017782794100389227,
};

// ---------------------------------------------------------------- utilities
__global__ void copy_f4(const float* __restrict__ src, float* __restrict__ dst, size_t n4) {
    size_t i = (size_t)blockIdx.x * blockDim.x + threadIdx.x;
    size_t stride = (size_t)gridDim.x * blockDim.x;
    for (; i < n4; i += stride)
        reinterpret_cast<float4*>(dst)[i] = reinterpret_cast<const float4*>(src)[i];
}

// ------------------------------------------------------------ generic GEMM
// C(MxN) = A(MxK) @ B(KxN) + bias(N). Row-major. 64x64 tile, BK=16,
// 256 threads, 4x4 micro-tile. All dims divisible by tile sizes here.
__global__ __launch_bounds__(256) void gemm64(const float* __restrict__ A,
        const float* __restrict__ B, const float* __restrict__ bias,
        float* __restrict__ C, int M, int N, int K)
{
    __shared__ float As[16][64];   // [k][m]
    __shared__ float Bs[16][64];   // [k][n]
    const int t  = threadIdx.x;
    const int m0 = blockIdx.y * 64;
    const int n0 = blockIdx.x * 64;
    const int tx = t & 15, ty = t >> 4;
    float acc[4][4] = {};

    for (int k0 = 0; k0 < K; k0 += 16) {
        // stage A tile (64x16) transposed into [k][m]
        {
            int m = t >> 2, k4 = (t & 3) * 4;
            float4 v = *reinterpret_cast<const float4*>(&A[(size_t)(m0 + m) * K + k0 + k4]);
            As[k4 + 0][m] = v.x; As[k4 + 1][m] = v.y;
            As[k4 + 2][m] = v.z; As[k4 + 3][m] = v.w;
            int kb = t >> 4, n4 = (t & 15) * 4;
            *reinterpret_cast<float4*>(&Bs[kb][n4]) =
                *reinterpret_cast<const float4*>(&B[(size_t)(k0 + kb) * N + n0 + n4]);
        }
        __syncthreads();
        #pragma unroll
        for (int k = 0; k < 16; ++k) {
            float a[4], b[4];
            *reinterpret_cast<float4*>(a) = *reinterpret_cast<const float4*>(&As[k][ty * 4]);
            *reinterpret_cast<float4*>(b) = *reinterpret_cast<const float4*>(&Bs[k][tx * 4]);
            #pragma unroll
            for (int i = 0; i < 4; ++i)
                #pragma unroll
                for (int j = 0; j < 4; ++j)
                    acc[i][j] = fmaf(a[i], b[j], acc[i][j]);
        }
        __syncthreads();
    }
    #pragma unroll
    for (int i = 0; i < 4; ++i) {
        int n = n0 + tx * 4;
        float4 o;
        o.x = acc[i][0] + bias[n + 0];
        o.y = acc[i][1] + bias[n + 1];
        o.z = acc[i][2] + bias[n + 2];
        o.w = acc[i][3] + bias[n + 3];
        *reinterpret_cast<float4*>(&C[(size_t)(m0 + ty * 4 + i) * N + n]) = o;
    }
}

// ------------------------------------------------------------------- RoPE
// In-place RoPE on a (rows, 512) matrix laid out as (rows, H=16, Dh=32).
// One thread per (row, h, j<16) pair handles elements j and j+16.
__global__ void rope_kernel(float* __restrict__ p, int rows) {
    int id = blockIdx.x * blockDim.x + threadIdx.x;
    int total = rows * NH * 16;
    if (id >= total) return;
    int j   = id & 15;
    int h   = (id >> 4) & 15;
    int row = id >> 8;
    float ang = (float)((double)row * c_invfreq[j]);
    float c = cosf(ang), s = sinf(ang);
    size_t base = (size_t)row * HDh + h * DH + j;
    float x1 = p[base], x2 = p[base + 16];
    p[base]      = x1 * c - x2 * s;
    p[base + 16] = x1 * s + x2 * c;
}

// ----------------------------------------------------------------- scores
// scores[h][q][k] = dot(q_rope[q, h*32:], k_rope[k, h*32:]) / sqrt(32)
// 64x64 output tile per block, K=32 fully in LDS.
__global__ __launch_bounds__(256) void scores_kernel(const float* __restrict__ qr,
        const float* __restrict__ kr, float* __restrict__ scores)
{
    __shared__ float Qs[32][64];   // [d][q-row]
    __shared__ float Ks[32][64];   // [d][k-row]
    const int h  = blockIdx.z;
    const int q0 = blockIdx.y * 64;
    const int k0 = blockIdx.x * 64;
    const int t  = threadIdx.x;
    #pragma unroll
    for (int i = 0; i < 2; ++i) {
        int f = t + 256 * i;               // 0..511
        int r = f >> 3, d4 = (f & 7) * 4;  // 64 rows x 8 float4
        float4 qv = *reinterpret_cast<const float4*>(&qr[(size_t)(q0 + r) * HDh + h * DH + d4]);
        Qs[d4 + 0][r] = qv.x; Qs[d4 + 1][r] = qv.y; Qs[d4 + 2][r] = qv.z; Qs[d4 + 3][r] = qv.w;
        float4 kv = *reinterpret_cast<const float4*>(&kr[(size_t)(k0 + r) * HDh + h * DH + d4]);
        Ks[d4 + 0][r] = kv.x; Ks[d4 + 1][r] = kv.y; Ks[d4 + 2][r] = kv.z; Ks[d4 + 3][r] = kv.w;
    }
    __syncthreads();
    const int tx = t & 15, ty = t >> 4;
    float acc[4][4] = {};
    #pragma unroll
    for (int d = 0; d < 32; ++d) {
        float a[4], b[4];
        *reinterpret_cast<float4*>(a) = *reinterpret_cast<const float4*>(&Qs[d][ty * 4]);
        *reinterpret_cast<float4*>(b) = *reinterpret_cast<const float4*>(&Ks[d][tx * 4]);
        #pragma unroll
        for (int i = 0; i < 4; ++i)
            #pragma unroll
            for (int j = 0; j < 4; ++j)
                acc[i][j] = fmaf(a[i], b[j], acc[i][j]);
    }
    const float sc = 0.17677669529663687f;  // 1/sqrt(32)
    float* obase = scores + (size_t)h * L_Q * KV_TOT;
    #pragma unroll
    for (int i = 0; i < 4; ++i) {
        float4 o = make_float4(acc[i][0] * sc, acc[i][1] * sc, acc[i][2] * sc, acc[i][3] * sc);
        *reinterpret_cast<float4*>(&obase[(size_t)(q0 + ty * 4 + i) * KV_TOT + k0 + tx * 4]) = o;
    }
}

// ---------------------------------------------------------------- softmax
__device__ inline float waveMax(float v) {
    #pragma unroll
    for (int o = 32; o > 0; o >>= 1) v = fmaxf(v, __shfl_xor(v, o, 64));
    return v;
}
__device__ inline float waveSum(float v) {
    #pragma unroll
    for (int o = 32; o > 0; o >>= 1) v += __shfl_xor(v, o, 64);
    return v;
}

// One block per (h, q) row of 4096. Writes unmasked softmax to attn,
// masked-softmax stats (max, 1/sum) to workspace.
__global__ __launch_bounds__(256) void softmax_kernel(const float* __restrict__ scores,
        const int* __restrict__ vlens, float* __restrict__ attn,
        float* __restrict__ mM, float* __restrict__ iS)
{
    __shared__ float red[4], red2[4];
    const int h = blockIdx.y, q = blockIdx.x;
    const float* row = scores + ((size_t)h * L_Q + q) * KV_TOT;
    float* arow = attn + ((size_t)h * L_Q + q) * KV_TOT;
    const int t = threadIdx.x;
    const int vl = vlens[q];

    float vals[16];
    #pragma unroll
    for (int jj = 0; jj < 4; ++jj)
        *reinterpret_cast<float4*>(&vals[jj * 4]) =
            *reinterpret_cast<const float4*>(&row[jj * 1024 + t * 4]);

    float mu = -3.4e38f, mm = -3.4e38f;
    #pragma unroll
    for (int jj = 0; jj < 4; ++jj)
        #pragma unroll
        for (int e = 0; e < 4; ++e) {
            int k = jj * 1024 + t * 4 + e;
            float v = vals[jj * 4 + e];
            mu = fmaxf(mu, v);
            if (k < vl) mm = fmaxf(mm, v);
        }
    mu = waveMax(mu); mm = waveMax(mm);
    int w = t >> 6;
    if ((t & 63) == 0) { red[w] = mu; red2[w] = mm; }
    __syncthreads();
    mu = fmaxf(fmaxf(red[0], red[1]), fmaxf(red[2], red[3]));
    mm = fmaxf(fmaxf(red2[0], red2[1]), fmaxf(red2[2], red2[3]));
    __syncthreads();

    float su = 0.f, sm = 0.f;
    float ev[16];
    #pragma unroll
    for (int jj = 0; jj < 4; ++jj)
        #pragma unroll
        for (int e = 0; e < 4; ++e) {
            int k = jj * 1024 + t * 4 + e;
            float v = vals[jj * 4 + e];
            float e1 = __expf(v - mu);
            ev[jj * 4 + e] = e1;
            su += e1;
            if (k < vl) sm += __expf(v - mm);
        }
    su = waveSum(su); sm = waveSum(sm);
    if ((t & 63) == 0) { red[w] = su; red2[w] = sm; }
    __syncthreads();
    su = red[0] + red[1] + red[2] + red[3];
    sm = red2[0] + red2[1] + red2[2] + red2[3];

    float isu = 1.f / su;
    #pragma unroll
    for (int jj = 0; jj < 4; ++jj) {
        float4 o;
        o.x = ev[jj * 4 + 0] * isu;
        o.y = ev[jj * 4 + 1] * isu;
        o.z = ev[jj * 4 + 2] * isu;
        o.w = ev[jj * 4 + 3] * isu;
        *reinterpret_cast<float4*>(&arow[jj * 1024 + t * 4]) = o;
    }
    if (t == 0) {
        mM[(size_t)h * L_Q + q] = mm;
        iS[(size_t)h * L_Q + q] = 1.f / sm;
    }
}

// ------------------------------------------------------------------ heads
// heads[q, h*32+c] = sum_k maskedW[h,q,k] * v[k, h*32+c]
// Per-block: one head, 128 q-rows, loop over k in tiles of 64.
// Masked weights recomputed from scores + stats (identical __expf as stats).
__global__ __launch_bounds__(256) void heads_kernel(const float* __restrict__ scores,
        const float* __restrict__ v, const int* __restrict__ vlens,
        const float* __restrict__ mM, const float* __restrict__ iS,
        float* __restrict__ heads)
{
    __shared__ float Wt[64][128];   // [k][q-row]  32 KB
    __shared__ float Vt[64][32];    // [k][c]       8 KB
    __shared__ float s_m[128], s_is[128];
    __shared__ int   s_vl[128];
    const int h  = blockIdx.y;
    const int q0 = blockIdx.x * 128;
    const int t  = threadIdx.x;
    if (t < 128) {
        s_m[t]  = mM[(size_t)h * L_Q + q0 + t];
        s_is[t] = iS[(size_t)h * L_Q + q0 + t];
        s_vl[t] = vlens[q0 + t];
    }
    __syncthreads();
    const int tr = t >> 3, tc = t & 7;   // 32 row-groups x 8 col-groups
    float acc[4][4] = {};
    const float* sbase = scores + (size_t)h * L_Q * KV_TOT;

    for (int k0 = 0; k0 < KV_TOT; k0 += 64) {
        #pragma unroll
        for (int i = 0; i < 8; ++i) {
            int f = t + 256 * i;                 // 0..2047 float4 units
            int r = f >> 4, k4 = (f & 15) * 4;   // 128 rows x 16 float4
            float4 sv = *reinterpret_cast<const float4*>(
                &sbase[(size_t)(q0 + r) * KV_TOT + k0 + k4]);
            float m = s_m[r], is = s_is[r];
            int vr = s_vl[r];
            int kk = k0 + k4;
            Wt[k4 + 0][r] = (kk + 0 < vr) ? __expf(sv.x - m) * is : 0.f;
            Wt[k4 + 1][r] = (kk + 1 < vr) ? __expf(sv.y - m) * is : 0.f;
            Wt[k4 + 2][r] = (kk + 2 < vr) ? __expf(sv.z - m) * is : 0.f;
            Wt[k4 + 3][r] = (kk + 3 < vr) ? __expf(sv.w - m) * is : 0.f;
        }
        #pragma unroll
        for (int i = 0; i < 2; ++i) {
            int f = t + 256 * i;                 // 0..511
            int kk = f >> 3, c4 = (f & 7) * 4;
            *reinterpret_cast<float4*>(&Vt[kk][c4]) =
                *reinterpret_cast<const float4*>(&v[(size_t)(k0 + kk) * HDh + h * DH + c4]);
        }
        __syncthreads();
        #pragma unroll
        for (int kk = 0; kk < 64; ++kk) {
            float a[4], b[4];
            *reinterpret_cast<float4*>(a) = *reinterpret_cast<const float4*>(&Wt[kk][tr * 4]);
            *reinterpret_cast<float4*>(b) = *reinterpret_cast<const float4*>(&Vt[kk][tc * 4]);
            #pragma unroll
            for (int i = 0; i < 4; ++i)
                #pragma unroll
                for (int j = 0; j < 4; ++j)
                    acc[i][j] = fmaf(a[i], b[j], acc[i][j]);
        }
        __syncthreads();
    }
    #pragma unroll
    for (int i = 0; i < 4; ++i)
        *reinterpret_cast<float4*>(&heads[(size_t)(q0 + tr * 4 + i) * HDh + h * DH + tc * 4]) =
            make_float4(acc[i][0], acc[i][1], acc[i][2], acc[i][3]);
}

// ------------------------------------------------------------------ launch
extern "C" void kernel_launch(void* const* d_in, const int* in_sizes, int n_in,
                              void* d_out, int out_size, void* d_ws, size_t ws_size,
                              hipStream_t stream) {
    const float* x       = (const float*)d_in[0];
    const float* z_cache = (const float*)d_in[1];
    const int*   vlens   = (const int*)  d_in[2];
    const float* W_lat   = (const float*)d_in[3];
    const float* b_lat   = (const float*)d_in[4];
    const float* W_q     = (const float*)d_in[5];
    const float* b_q     = (const float*)d_in[6];
    const float* W_k     = (const float*)d_in[7];
    const float* b_k     = (const float*)d_in[8];
    const float* W_v     = (const float*)d_in[9];
    const float* b_v     = (const float*)d_in[10];
    const float* W_o     = (const float*)d_in[11];
    const float* b_o     = (const float*)d_in[12];

    float* out        = (float*)d_out;
    float* out_output = out;                                    // (2048, 2048)
    float* out_z      = out_output + (size_t)L_Q * DIM;         // (4096, 512)
    float* out_attn   = out_z + (size_t)KV_TOT * D_KV;          // (16, 2048, 4096)
    float* out_scores = out_attn + (size_t)NH * L_Q * KV_TOT;   // (16, 2048, 4096)

    // workspace: ~25.4 MB of f32
    float* ws       = (float*)d_ws;
    float* ws_q     = ws;                                  // 2048*512
    float* ws_k     = ws_q + (size_t)L_Q * HDh;            // 4096*512
    float* ws_v     = ws_k + (size_t)KV_TOT * HDh;         // 4096*512
    float* ws_heads = ws_v + (size_t)KV_TOT * HDh;         // 2048*512
    float* ws_mM    = ws_heads + (size_t)L_Q * HDh;        // 16*2048
    float* ws_iS    = ws_mM + (size_t)NH * L_Q;            // 16*2048

    // 1. z = concat(z_cache, x @ W_latent + b_latent)
    copy_f4<<<512, 256, 0, stream>>>(z_cache, out_z, (size_t)KV_PREV * D_KV / 4);
    gemm64<<<dim3(D_KV / 64, L_Q / 64), 256, 0, stream>>>(
        x, W_lat, b_lat, out_z + (size_t)KV_PREV * D_KV, L_Q, D_KV, DIM);

    // 2. q = rope(x @ W_q + b_q)
    gemm64<<<dim3(HDh / 64, L_Q / 64), 256, 0, stream>>>(x, W_q, b_q, ws_q, L_Q, HDh, DIM);
    rope_kernel<<<(L_Q * NH * 16) / 256, 256, 0, stream>>>(ws_q, L_Q);

    // 3. k = rope(z @ W_k + b_k), v = z @ W_v + b_v
    gemm64<<<dim3(HDh / 64, KV_TOT / 64), 256, 0, stream>>>(out_z, W_k, b_k, ws_k, KV_TOT, HDh, D_KV);
    rope_kernel<<<(KV_TOT * NH * 16) / 256, 256, 0, stream>>>(ws_k, KV_TOT);
    gemm64<<<dim3(HDh / 64, KV_TOT / 64), 256, 0, stream>>>(out_z, W_v, b_v, ws_v, KV_TOT, HDh, D_KV);

    // 4. scores
    scores_kernel<<<dim3(KV_TOT / 64, L_Q / 64, NH), 256, 0, stream>>>(ws_q, ws_k, out_scores);

    // 5. softmax (unmasked -> attn output; masked stats -> ws)
    softmax_kernel<<<dim3(L_Q, NH), 256, 0, stream>>>(out_scores, vlens, out_attn, ws_mM, ws_iS);

    // 6. heads = masked_softmax(scores) @ v
    heads_kernel<<<dim3(L_Q / 128, NH), 256, 0, stream>>>(
        out_scores, ws_v, vlens, ws_mM, ws_iS, ws_heads);

    // 7. output = heads @ W_o + b_o
    gemm64<<<dim3(DIM / 64, L_Q / 64), 256, 0, stream>>>(ws_heads, W_o, b_o, out_output, L_Q, DIM, HDh);
}

// Round 2
// 804.313 us; speedup vs baseline: 1.5525x; 1.5525x over previous
//
#include <hip/hip_runtime.h>
#include <math.h>

// Problem constants (B=1)
#define L_Q     2048
#define KV_PREV 2048
#define KV_TOT  4096
#define DIM     2048
#define D_KV    512
#define NH      16
#define DH      32
#define HDh     512   // NH*DH

typedef short bf16x8 __attribute__((ext_vector_type(8)));
typedef float f32x4  __attribute__((ext_vector_type(4)));

__device__ inline short f2bf(float f) {   // RNE float -> bf16 bits
    unsigned u = __float_as_uint(f);
    u += 0x7fff + ((u >> 16) & 1);
    return (short)(u >> 16);
}

// inv_freq[j] = 10000^(-j/16) = 10^(-j/4), precomputed in double.
__device__ __constant__ double c_invfreq[16] = {
    1.0, 0.5623413251903491, 0.31622776601683794, 0.17782794100389228,
    0.1, 0.05623413251903491, 0.03162277660168379, 0.017782794100389228,
    0.01, 0.005623413251903491, 0.0031622776601683794, 0.0017782794100389228,
    0.001, 0.0005623413251903491, 0.00031622776601683794, 0.00017782794100389227,
};

// ---------------------------------------------------------------- utilities
__global__ void copy_f4(const float* __restrict__ src, float* __restrict__ dst, size_t n4) {
    size_t i = (size_t)blockIdx.x * blockDim.x + threadIdx.x;
    size_t stride = (size_t)gridDim.x * blockDim.x;
    for (; i < n4; i += stride)
        reinterpret_cast<float4*>(dst)[i] = reinterpret_cast<const float4*>(src)[i];
}

__global__ void cvt_bf16(const float* __restrict__ in, short* __restrict__ out, int n8) {
    int i = blockIdx.x * blockDim.x + threadIdx.x;
    if (i >= n8) return;
    float4 a = reinterpret_cast<const float4*>(in)[2 * i];
    float4 b = reinterpret_cast<const float4*>(in)[2 * i + 1];
    union { short s[8]; int4 v; } u;
    u.s[0] = f2bf(a.x); u.s[1] = f2bf(a.y); u.s[2] = f2bf(a.z); u.s[3] = f2bf(a.w);
    u.s[4] = f2bf(b.x); u.s[5] = f2bf(b.y); u.s[6] = f2bf(b.z); u.s[7] = f2bf(b.w);
    reinterpret_cast<int4*>(out)[i] = u.v;
}

// in: [K][N] f32 row-major -> out: [N][K] bf16 (transposed weight)
__global__ __launch_bounds__(256) void tr_cvt(const float* __restrict__ in,
        short* __restrict__ out, int K, int N) {
    __shared__ float tile[32][33];
    int k0 = blockIdx.x * 32, n0 = blockIdx.y * 32;
    int c = threadIdx.x & 31, r0 = threadIdx.x >> 5;
    for (int r = r0; r < 32; r += 8)
        tile[r][c] = in[(size_t)(k0 + r) * N + n0 + c];
    __syncthreads();
    for (int r = r0; r < 32; r += 8)
        out[(size_t)(n0 + r) * K + k0 + c] = f2bf(tile[c][r]);
}

// RoPE on (rows,512)=[rows][H=16][Dh=32] f32, writing bf16.
__global__ void rope_cvt(const float* __restrict__ in, short* __restrict__ out, int rows) {
    int id = blockIdx.x * blockDim.x + threadIdx.x;
    if (id >= rows * NH * 16) return;
    int j   = id & 15;
    int h   = (id >> 4) & 15;
    int row = id >> 8;
    float ang = (float)((double)row * c_invfreq[j]);
    float c = cosf(ang), s = sinf(ang);
    size_t base = (size_t)row * HDh + h * DH + j;
    float x1 = in[base], x2 = in[base + 16];
    out[base]      = f2bf(x1 * c - x2 * s);
    out[base + 16] = f2bf(x1 * s + x2 * c);
}

// v: [KV][512] f32 -> Vt: [NH][32][KV] bf16 (per-head transposed V)
__global__ __launch_bounds__(256) void vt_cvt(const float* __restrict__ v, short* __restrict__ vt) {
    __shared__ float tile[64][33];
    int h = blockIdx.y, kv0 = blockIdx.x * 64;
    int c = threadIdx.x & 31, r0 = threadIdx.x >> 5;
    for (int r = r0; r < 64; r += 8)
        tile[r][c] = v[(size_t)(kv0 + r) * HDh + h * DH + c];
    __syncthreads();
    int l = threadIdx.x & 63, wv = threadIdx.x >> 6;
    for (int d = wv; d < 32; d += 4)
        vt[((size_t)h * DH + d) * KV_TOT + kv0 + l] = f2bf(tile[l][d]);
}

// ------------------------------------------------- bf16 MFMA projection GEMM
// C(MxN) f32 = A(MxK) bf16 @ Bt(NxK) bf16^T + bias. Block 64x64, 4 waves.
__global__ __launch_bounds__(256) void gemm_bf16(const short* __restrict__ A,
        const short* __restrict__ Bt, const float* __restrict__ bias,
        float* __restrict__ C, int M, int N, int K)
{
    int t = threadIdx.x, w = t >> 6, l = t & 63, lr = l & 15, lg = l >> 4;
    int m0 = blockIdx.y * 64 + w * 16;
    int n0 = blockIdx.x * 64;
    f32x4 acc[4] = {{0,0,0,0},{0,0,0,0},{0,0,0,0},{0,0,0,0}};
    const short* ap  = A  + (size_t)(m0 + lr) * K + lg * 8;
    const short* bp0 = Bt + (size_t)(n0 + lr) * K + lg * 8;
    for (int k0 = 0; k0 < K; k0 += 32) {
        bf16x8 a = *reinterpret_cast<const bf16x8*>(ap + k0);
        #pragma unroll
        for (int j = 0; j < 4; ++j) {
            bf16x8 b = *reinterpret_cast<const bf16x8*>(bp0 + (size_t)j * 16 * K + k0);
            acc[j] = __builtin_amdgcn_mfma_f32_16x16x32_bf16(a, b, acc[j], 0, 0, 0);
        }
    }
    #pragma unroll
    for (int j = 0; j < 4; ++j) {
        int n = n0 + j * 16 + lr;
        float bs = bias[n];
        #pragma unroll
        for (int r = 0; r < 4; ++r)
            C[(size_t)(m0 + lg * 4 + r) * N + n] = acc[j][r] + bs;
    }
}

// ---------------------------------------- K1: scores + online softmax sums
// Per (h, 64-q block). Writes scaled scores; accumulates su=Sum exp(s) and
// s2=Sum_{k<vl} exp(s) per row (no max shift: |s|<~10, no overflow possible).
__global__ __launch_bounds__(256) void scores_stats(const short* __restrict__ q,
        const short* __restrict__ kmat, const int* __restrict__ vlens,
        float* __restrict__ scores, float* __restrict__ isu_o, float* __restrict__ is2_o)
{
    int t = threadIdx.x, w = t >> 6, l = t & 63, lr = l & 15, lg = l >> 4;
    int h = blockIdx.y;
    int qrow = blockIdx.x * 64 + w * 16;
    bf16x8 aQ = *reinterpret_cast<const bf16x8*>(q + (size_t)(qrow + lr) * HDh + h * DH + lg * 8);
    int myrow = qrow + lg * 4;
    int vl[4];
    float su[4] = {0,0,0,0}, s2[4] = {0,0,0,0};
    #pragma unroll
    for (int r = 0; r < 4; ++r) vl[r] = vlens[myrow + r];
    float* sp = scores + ((size_t)h * L_Q + myrow) * KV_TOT + lr;
    const short* kp = kmat + (size_t)lr * HDh + h * DH + lg * 8;
    const float sc = 0.17677669529663687f;  // 1/sqrt(32)
    for (int k0 = 0; k0 < KV_TOT; k0 += 16) {
        bf16x8 bK = *reinterpret_cast<const bf16x8*>(kp + (size_t)k0 * HDh);
        f32x4 zz = {0.f, 0.f, 0.f, 0.f};
        f32x4 s = __builtin_amdgcn_mfma_f32_16x16x32_bf16(aQ, bK, zz, 0, 0, 0);
        int col = k0 + lr;
        #pragma unroll
        for (int r = 0; r < 4; ++r) {
            float v = s[r] * sc;
            sp[(size_t)r * KV_TOT + k0] = v;
            float e = __expf(v);
            su[r] += e;
            if (col < vl[r]) s2[r] += e;
        }
    }
    #pragma unroll
    for (int m = 1; m < 16; m <<= 1)
        #pragma unroll
        for (int r = 0; r < 4; ++r) {
            su[r] += __shfl_xor(su[r], m, 64);
            s2[r] += __shfl_xor(s2[r], m, 64);
        }
    if (lr == 0) {
        #pragma unroll
        for (int r = 0; r < 4; ++r) {
            size_t idx = (size_t)h * L_Q + myrow + r;
            isu_o[idx] = 1.f / su[r];
            is2_o[idx] = 1.f / s2[r];
        }
    }
}

// ------------------------------- K2: attn write + masked-softmax PV (MFMA)
__global__ __launch_bounds__(256) void attn_pv(const float* __restrict__ scores,
        const int* __restrict__ vlens, const float* __restrict__ isu_i,
        const float* __restrict__ is2_i, const short* __restrict__ Vt,
        float* __restrict__ attn, short* __restrict__ heads_bf)
{
    int t = threadIdx.x, w = t >> 6, l = t & 63, lr = l & 15, lg = l >> 4;
    int h = blockIdx.y;
    int qrow = blockIdx.x * 64 + w * 16;
    int arow = qrow + lr;
    size_t sidx = (size_t)h * L_Q + arow;
    float isu = isu_i[sidx], is2 = is2_i[sidx];
    int vl = vlens[arow];
    const float* srow = scores + sidx * KV_TOT + lg * 8;
    float* atrow = attn + sidx * KV_TOT + lg * 8;
    const short* vp0 = Vt + ((size_t)h * DH + lr) * KV_TOT + lg * 8;
    const short* vp1 = vp0 + (size_t)16 * KV_TOT;
    f32x4 h0 = {0,0,0,0}, h1 = {0,0,0,0};
    for (int k0 = 0; k0 < KV_TOT; k0 += 32) {
        float4 sA = *reinterpret_cast<const float4*>(srow + k0);
        float4 sB = *reinterpret_cast<const float4*>(srow + k0 + 4);
        float e[8] = { __expf(sA.x), __expf(sA.y), __expf(sA.z), __expf(sA.w),
                       __expf(sB.x), __expf(sB.y), __expf(sB.z), __expf(sB.w) };
        int kb = k0 + lg * 8;
        *reinterpret_cast<float4*>(atrow + k0) =
            make_float4(e[0] * isu, e[1] * isu, e[2] * isu, e[3] * isu);
        *reinterpret_cast<float4*>(atrow + k0 + 4) =
            make_float4(e[4] * isu, e[5] * isu, e[6] * isu, e[7] * isu);
        union { short s[8]; bf16x8 v; } pw;
        #pragma unroll
        for (int i = 0; i < 8; ++i)
            pw.s[i] = (kb + i < vl) ? f2bf(e[i] * is2) : (short)0;
        bf16x8 b0 = *reinterpret_cast<const bf16x8*>(vp0 + k0);
        bf16x8 b1 = *reinterpret_cast<const bf16x8*>(vp1 + k0);
        h0 = __builtin_amdgcn_mfma_f32_16x16x32_bf16(pw.v, b0, h0, 0, 0, 0);
        h1 = __builtin_amdgcn_mfma_f32_16x16x32_bf16(pw.v, b1, h1, 0, 0, 0);
    }
    #pragma unroll
    for (int r = 0; r < 4; ++r) {
        size_t ho = (size_t)(qrow + lg * 4 + r) * HDh + h * DH + lr;
        heads_bf[ho]      = f2bf(h0[r]);
        heads_bf[ho + 16] = f2bf(h1[r]);
    }
}

// ------------------------------------------------------------------ launch
extern "C" void kernel_launch(void* const* d_in, const int* in_sizes, int n_in,
                              void* d_out, int out_size, void* d_ws, size_t ws_size,
                              hipStream_t stream) {
    const float* x       = (const float*)d_in[0];
    const float* z_cache = (const float*)d_in[1];
    const int*   vlens   = (const int*)  d_in[2];
    const float* W_lat   = (const float*)d_in[3];
    const float* b_lat   = (const float*)d_in[4];
    const float* W_q     = (const float*)d_in[5];
    const float* b_q     = (const float*)d_in[6];
    const float* W_k     = (const float*)d_in[7];
    const float* b_k     = (const float*)d_in[8];
    const float* W_v     = (const float*)d_in[9];
    const float* b_v     = (const float*)d_in[10];
    const float* W_o     = (const float*)d_in[11];
    const float* b_o     = (const float*)d_in[12];

    float* out        = (float*)d_out;
    float* out_output = out;                                    // (2048, 2048)
    float* out_z      = out_output + (size_t)L_Q * DIM;         // (4096, 512)
    float* out_attn   = out_z + (size_t)KV_TOT * D_KV;          // (16, 2048, 4096)
    float* out_scores = out_attn + (size_t)NH * L_Q * KV_TOT;   // (16, 2048, 4096)

    // ---- workspace layout (f32 region then bf16 region), ~53 MB
    float* wf     = (float*)d_ws;
    float* ws_qf  = wf;                               // 2048*512
    float* ws_kf  = ws_qf + (size_t)L_Q * HDh;        // 4096*512
    float* ws_vf  = ws_kf + (size_t)KV_TOT * HDh;     // 4096*512
    float* ws_isu = ws_vf + (size_t)KV_TOT * HDh;     // 16*2048
    float* ws_is2 = ws_isu + (size_t)NH * L_Q;        // 16*2048
    short* wsb      = (short*)(ws_is2 + (size_t)NH * L_Q);
    short* x_bf     = wsb;                              // 2048*2048
    short* z_bf     = x_bf + (size_t)L_Q * DIM;         // 4096*512
    short* q_bf     = z_bf + (size_t)KV_TOT * D_KV;     // 2048*512
    short* k_bf     = q_bf + (size_t)L_Q * HDh;         // 4096*512
    short* Vt       = k_bf + (size_t)KV_TOT * HDh;      // 16*32*4096
    short* heads_bf = Vt + (size_t)NH * DH * KV_TOT;    // 2048*512
    short* Wt_lat   = heads_bf + (size_t)L_Q * HDh;     // 512*2048
    short* Wt_q     = Wt_lat + (size_t)D_KV * DIM;      // 512*2048
    short* Wt_k     = Wt_q + (size_t)HDh * DIM;         // 512*512
    short* Wt_v     = Wt_k + (size_t)HDh * D_KV;        // 512*512
    short* Wt_o     = Wt_v + (size_t)HDh * D_KV;        // 2048*512

    // ---- prep: conversions / transposes
    cvt_bf16<<<(L_Q * DIM / 8 + 255) / 256, 256, 0, stream>>>(x, x_bf, L_Q * DIM / 8);
    tr_cvt<<<dim3(DIM / 32, D_KV / 32), 256, 0, stream>>>(W_lat, Wt_lat, DIM, D_KV);
    tr_cvt<<<dim3(DIM / 32, HDh / 32), 256, 0, stream>>>(W_q, Wt_q, DIM, HDh);
    tr_cvt<<<dim3(D_KV / 32, HDh / 32), 256, 0, stream>>>(W_k, Wt_k, D_KV, HDh);
    tr_cvt<<<dim3(D_KV / 32, HDh / 32), 256, 0, stream>>>(W_v, Wt_v, D_KV, HDh);
    tr_cvt<<<dim3(HDh / 32, DIM / 32), 256, 0, stream>>>(W_o, Wt_o, HDh, DIM);

    // ---- z = concat(z_cache, x @ W_latent + b_latent); z_bf copy
    copy_f4<<<512, 256, 0, stream>>>(z_cache, out_z, (size_t)KV_PREV * D_KV / 4);
    gemm_bf16<<<dim3(D_KV / 64, L_Q / 64), 256, 0, stream>>>(
        x_bf, Wt_lat, b_lat, out_z + (size_t)KV_PREV * D_KV, L_Q, D_KV, DIM);
    cvt_bf16<<<(KV_TOT * D_KV / 8 + 255) / 256, 256, 0, stream>>>(out_z, z_bf, KV_TOT * D_KV / 8);

    // ---- projections + rope + V transpose
    gemm_bf16<<<dim3(HDh / 64, L_Q / 64), 256, 0, stream>>>(x_bf, Wt_q, b_q, ws_qf, L_Q, HDh, DIM);
    rope_cvt<<<(L_Q * 256) / 256, 256, 0, stream>>>(ws_qf, q_bf, L_Q);
    gemm_bf16<<<dim3(HDh / 64, KV_TOT / 64), 256, 0, stream>>>(z_bf, Wt_k, b_k, ws_kf, KV_TOT, HDh, D_KV);
    rope_cvt<<<(KV_TOT * 256) / 256, 256, 0, stream>>>(ws_kf, k_bf, KV_TOT);
    gemm_bf16<<<dim3(HDh / 64, KV_TOT / 64), 256, 0, stream>>>(z_bf, Wt_v, b_v, ws_vf, KV_TOT, HDh, D_KV);
    vt_cvt<<<dim3(KV_TOT / 64, NH), 256, 0, stream>>>(ws_vf, Vt);

    // ---- K1: scores + softmax sums
    scores_stats<<<dim3(L_Q / 64, NH), 256, 0, stream>>>(
        q_bf, k_bf, vlens, out_scores, ws_isu, ws_is2);

    // ---- K2: attn weights + PV
    attn_pv<<<dim3(L_Q / 64, NH), 256, 0, stream>>>(
        out_scores, vlens, ws_isu, ws_is2, Vt, out_attn, heads_bf);

    // ---- output projection
    gemm_bf16<<<dim3(DIM / 64, L_Q / 64), 256, 0, stream>>>(
        heads_bf, Wt_o, b_o, out_output, L_Q, DIM, HDh);
}

// Round 3
// 724.849 us; speedup vs baseline: 1.7227x; 1.1096x over previous
//
#include <hip/hip_runtime.h>
#include <math.h>

// Problem constants (B=1)
#define L_Q     2048
#define KV_PREV 2048
#define KV_TOT  4096
#define DIM     2048
#define D_KV    512
#define NH      16
#define DH      32
#define HDh     512   // NH*DH

typedef short bf16x8 __attribute__((ext_vector_type(8)));
typedef float f32x4  __attribute__((ext_vector_type(4)));

__device__ inline short f2bf(float f) {   // RNE float -> bf16 bits
    unsigned u = __float_as_uint(f);
    u += 0x7fff + ((u >> 16) & 1);
    return (short)(u >> 16);
}

// inv_freq[j] = 10000^(-j/16) = 10^(-j/4), precomputed in double.
__device__ __constant__ double c_invfreq[16] = {
    1.0, 0.5623413251903491, 0.31622776601683794, 0.17782794100389228,
    0.1, 0.05623413251903491, 0.03162277660168379, 0.017782794100389228,
    0.01, 0.005623413251903491, 0.0031622776601683794, 0.0017782794100389228,
    0.001, 0.0005623413251903491, 0.00031622776601683794, 0.00017782794100389227,
};

// ---------------------------------------------------------------- utilities
__global__ void copy_f4(const float* __restrict__ src, float* __restrict__ dst, size_t n4) {
    size_t i = (size_t)blockIdx.x * blockDim.x + threadIdx.x;
    size_t stride = (size_t)gridDim.x * blockDim.x;
    for (; i < n4; i += stride)
        reinterpret_cast<float4*>(dst)[i] = reinterpret_cast<const float4*>(src)[i];
}

__global__ void cvt_bf16(const float* __restrict__ in, short* __restrict__ out, int n8) {
    int i = blockIdx.x * blockDim.x + threadIdx.x;
    if (i >= n8) return;
    float4 a = reinterpret_cast<const float4*>(in)[2 * i];
    float4 b = reinterpret_cast<const float4*>(in)[2 * i + 1];
    union { short s[8]; int4 v; } u;
    u.s[0] = f2bf(a.x); u.s[1] = f2bf(a.y); u.s[2] = f2bf(a.z); u.s[3] = f2bf(a.w);
    u.s[4] = f2bf(b.x); u.s[5] = f2bf(b.y); u.s[6] = f2bf(b.z); u.s[7] = f2bf(b.w);
    reinterpret_cast<int4*>(out)[i] = u.v;
}

// in: [K][N] f32 row-major -> out: [N][K] bf16 (transposed weight)
__global__ __launch_bounds__(256) void tr_cvt(const float* __restrict__ in,
        short* __restrict__ out, int K, int N) {
    __shared__ float tile[32][33];
    int k0 = blockIdx.x * 32, n0 = blockIdx.y * 32;
    int c = threadIdx.x & 31, r0 = threadIdx.x >> 5;
    for (int r = r0; r < 32; r += 8)
        tile[r][c] = in[(size_t)(k0 + r) * N + n0 + c];
    __syncthreads();
    for (int r = r0; r < 32; r += 8)
        out[(size_t)(n0 + r) * K + k0 + c] = f2bf(tile[c][r]);
}

// RoPE on (rows,512)=[rows][H=16][Dh=32] f32, writing bf16.
__global__ void rope_cvt(const float* __restrict__ in, short* __restrict__ out, int rows) {
    int id = blockIdx.x * blockDim.x + threadIdx.x;
    if (id >= rows * NH * 16) return;
    int j   = id & 15;
    int h   = (id >> 4) & 15;
    int row = id >> 8;
    float ang = (float)((double)row * c_invfreq[j]);
    float c = cosf(ang), s = sinf(ang);
    size_t base = (size_t)row * HDh + h * DH + j;
    float x1 = in[base], x2 = in[base + 16];
    out[base]      = f2bf(x1 * c - x2 * s);
    out[base + 16] = f2bf(x1 * s + x2 * c);
}

// v: [KV][512] f32 -> Vt: [NH][32][KV] bf16 (per-head transposed V)
__global__ __launch_bounds__(256) void vt_cvt(const float* __restrict__ v, short* __restrict__ vt) {
    __shared__ float tile[64][33];
    int h = blockIdx.y, kv0 = blockIdx.x * 64;
    int c = threadIdx.x & 31, r0 = threadIdx.x >> 5;
    for (int r = r0; r < 64; r += 8)
        tile[r][c] = v[(size_t)(kv0 + r) * HDh + h * DH + c];
    __syncthreads();
    int l = threadIdx.x & 63, wv = threadIdx.x >> 6;
    for (int d = wv; d < 32; d += 4)
        vt[((size_t)h * DH + d) * KV_TOT + kv0 + l] = f2bf(tile[l][d]);
}

// ------------------------------------------------- bf16 MFMA projection GEMM
// C(MxN) f32 = A(MxK) bf16 @ Bt(NxK) bf16^T + bias. Block 64x64, 4 waves.
// Optional bf16 mirror write (Cbf != nullptr).
__global__ __launch_bounds__(256) void gemm_bf16(const short* __restrict__ A,
        const short* __restrict__ Bt, const float* __restrict__ bias,
        float* __restrict__ C, short* __restrict__ Cbf, int M, int N, int K)
{
    int t = threadIdx.x, w = t >> 6, l = t & 63, lr = l & 15, lg = l >> 4;
    int m0 = blockIdx.y * 64 + w * 16;
    int n0 = blockIdx.x * 64;
    f32x4 acc[4] = {{0,0,0,0},{0,0,0,0},{0,0,0,0},{0,0,0,0}};
    const short* ap  = A  + (size_t)(m0 + lr) * K + lg * 8;
    const short* bp0 = Bt + (size_t)(n0 + lr) * K + lg * 8;
    #pragma unroll 2
    for (int k0 = 0; k0 < K; k0 += 32) {
        bf16x8 a = *reinterpret_cast<const bf16x8*>(ap + k0);
        #pragma unroll
        for (int j = 0; j < 4; ++j) {
            bf16x8 b = *reinterpret_cast<const bf16x8*>(bp0 + (size_t)j * 16 * K + k0);
            acc[j] = __builtin_amdgcn_mfma_f32_16x16x32_bf16(a, b, acc[j], 0, 0, 0);
        }
    }
    #pragma unroll
    for (int j = 0; j < 4; ++j) {
        int n = n0 + j * 16 + lr;
        float bs = bias[n];
        #pragma unroll
        for (int r = 0; r < 4; ++r) {
            float v = acc[j][r] + bs;
            size_t idx = (size_t)(m0 + lg * 4 + r) * N + n;
            C[idx] = v;
            if (Cbf) Cbf[idx] = f2bf(v);
        }
    }
}

// ---------------------------------------- K1: scores + online softmax sums
// Per (h, 64-q block). Writes scaled scores; accumulates su=Sum exp(s) and
// s2=Sum_{k<vl} exp(s) per row (no max shift: |s|<~10, no overflow possible).
__global__ __launch_bounds__(256) void scores_stats(const short* __restrict__ q,
        const short* __restrict__ kmat, const int* __restrict__ vlens,
        float* __restrict__ scores, float* __restrict__ isu_o, float* __restrict__ is2_o)
{
    int t = threadIdx.x, w = t >> 6, l = t & 63, lr = l & 15, lg = l >> 4;
    int h = blockIdx.y;
    int qrow = blockIdx.x * 64 + w * 16;
    bf16x8 aQ = *reinterpret_cast<const bf16x8*>(q + (size_t)(qrow + lr) * HDh + h * DH + lg * 8);
    int myrow = qrow + lg * 4;
    int vl[4];
    float su[4] = {0,0,0,0}, s2[4] = {0,0,0,0};
    #pragma unroll
    for (int r = 0; r < 4; ++r) vl[r] = vlens[myrow + r];
    float* sp = scores + ((size_t)h * L_Q + myrow) * KV_TOT + lr;
    const short* kp = kmat + (size_t)lr * HDh + h * DH + lg * 8;
    const float sc = 0.17677669529663687f;  // 1/sqrt(32)
    for (int k0 = 0; k0 < KV_TOT; k0 += 16) {
        bf16x8 bK = *reinterpret_cast<const bf16x8*>(kp + (size_t)k0 * HDh);
        f32x4 zz = {0.f, 0.f, 0.f, 0.f};
        f32x4 s = __builtin_amdgcn_mfma_f32_16x16x32_bf16(aQ, bK, zz, 0, 0, 0);
        int col = k0 + lr;
        #pragma unroll
        for (int r = 0; r < 4; ++r) {
            float v = s[r] * sc;
            __builtin_nontemporal_store(v, &sp[(size_t)r * KV_TOT + k0]);
            float e = __expf(v);
            su[r] += e;
            if (col < vl[r]) s2[r] += e;
        }
    }
    #pragma unroll
    for (int m = 1; m < 16; m <<= 1)
        #pragma unroll
        for (int r = 0; r < 4; ++r) {
            su[r] += __shfl_xor(su[r], m, 64);
            s2[r] += __shfl_xor(s2[r], m, 64);
        }
    if (lr == 0) {
        #pragma unroll
        for (int r = 0; r < 4; ++r) {
            size_t idx = (size_t)h * L_Q + myrow + r;
            isu_o[idx] = 1.f / su[r];
            is2_o[idx] = 1.f / s2[r];
        }
    }
}

// --------------------- K2: recompute scores, write attn, masked PV (MFMA)
// Per (h, 64-q block), 4 waves. QK^T recomputed bit-identically to K1 from
// L2-resident q_bf/k_bf (saves the 537 MB HBM scores re-read). P transposed
// to A-fragment layout via a wave-private padded LDS tile (no barrier).
__global__ __launch_bounds__(256) void attn_pv(const short* __restrict__ q,
        const short* __restrict__ kmat, const int* __restrict__ vlens,
        const float* __restrict__ isu_i, const float* __restrict__ is2_i,
        const short* __restrict__ Vt,
        float* __restrict__ attn, short* __restrict__ heads_bf)
{
    __shared__ short Plds[4][16][72];   // per-wave [q-row][k], pad 64->72
    int t = threadIdx.x, w = t >> 6, l = t & 63, lr = l & 15, lg = l >> 4;
    int h = blockIdx.y;
    int qrow = blockIdx.x * 64 + w * 16;

    bf16x8 aQ = *reinterpret_cast<const bf16x8*>(q + (size_t)(qrow + lr) * HDh + h * DH + lg * 8);
    const short* kp  = kmat + (size_t)lr * HDh + h * DH + lg * 8;
    const short* vp0 = Vt + ((size_t)h * DH + lr) * KV_TOT + lg * 8;       // d = lr
    const short* vp1 = vp0 + (size_t)16 * KV_TOT;                          // d = 16+lr

    int myrow = qrow + lg * 4;
    float isu_r[4], is2_r[4];
    int vl_r[4];
    #pragma unroll
    for (int r = 0; r < 4; ++r) {
        size_t idx = (size_t)h * L_Q + myrow + r;
        isu_r[r] = isu_i[idx];
        is2_r[r] = is2_i[idx];
        vl_r[r]  = vlens[myrow + r];
    }
    float* ap_ = attn + ((size_t)h * L_Q + myrow) * KV_TOT + lr;
    const float sc = 0.17677669529663687f;

    f32x4 h0 = {0,0,0,0}, h1 = {0,0,0,0};
    for (int k0 = 0; k0 < KV_TOT; k0 += 64) {
        // ---- 4 x QK^T 16x16 sub-blocks: exp, attn write, P^T into LDS
        #pragma unroll
        for (int kb = 0; kb < 4; ++kb) {
            int kk = k0 + kb * 16;
            bf16x8 bK = *reinterpret_cast<const bf16x8*>(kp + (size_t)kk * HDh);
            f32x4 zz = {0.f, 0.f, 0.f, 0.f};
            f32x4 s = __builtin_amdgcn_mfma_f32_16x16x32_bf16(aQ, bK, zz, 0, 0, 0);
            int col = kk + lr;
            #pragma unroll
            for (int r = 0; r < 4; ++r) {
                float v = s[r] * sc;
                float e = __expf(v);
                __builtin_nontemporal_store(e * isu_r[r], &ap_[(size_t)r * KV_TOT + kk]);
                short pb = (col < vl_r[r]) ? f2bf(e * is2_r[r]) : (short)0;
                Plds[w][lg * 4 + r][kb * 16 + lr] = pb;
            }
        }
        // ---- PV: read A-fragments from LDS (wave-private, no barrier)
        #pragma unroll
        for (int kb2 = 0; kb2 < 2; ++kb2) {
            bf16x8 pa = *reinterpret_cast<const bf16x8*>(&Plds[w][lr][kb2 * 32 + lg * 8]);
            bf16x8 b0 = *reinterpret_cast<const bf16x8*>(vp0 + k0 + kb2 * 32);
            bf16x8 b1 = *reinterpret_cast<const bf16x8*>(vp1 + k0 + kb2 * 32);
            h0 = __builtin_amdgcn_mfma_f32_16x16x32_bf16(pa, b0, h0, 0, 0, 0);
            h1 = __builtin_amdgcn_mfma_f32_16x16x32_bf16(pa, b1, h1, 0, 0, 0);
        }
    }
    // D: col = d = lr, row = q = lg*4+r
    #pragma unroll
    for (int r = 0; r < 4; ++r) {
        size_t ho = (size_t)(qrow + lg * 4 + r) * HDh + h * DH + lr;
        heads_bf[ho]      = f2bf(h0[r]);
        heads_bf[ho + 16] = f2bf(h1[r]);
    }
}

// ------------------------------------------------------------------ launch
extern "C" void kernel_launch(void* const* d_in, const int* in_sizes, int n_in,
                              void* d_out, int out_size, void* d_ws, size_t ws_size,
                              hipStream_t stream) {
    const float* x       = (const float*)d_in[0];
    const float* z_cache = (const float*)d_in[1];
    const int*   vlens   = (const int*)  d_in[2];
    const float* W_lat   = (const float*)d_in[3];
    const float* b_lat   = (const float*)d_in[4];
    const float* W_q     = (const float*)d_in[5];
    const float* b_q     = (const float*)d_in[6];
    const float* W_k     = (const float*)d_in[7];
    const float* b_k     = (const float*)d_in[8];
    const float* W_v     = (const float*)d_in[9];
    const float* b_v     = (const float*)d_in[10];
    const float* W_o     = (const float*)d_in[11];
    const float* b_o     = (const float*)d_in[12];

    float* out        = (float*)d_out;
    float* out_output = out;                                    // (2048, 2048)
    float* out_z      = out_output + (size_t)L_Q * DIM;         // (4096, 512)
    float* out_attn   = out_z + (size_t)KV_TOT * D_KV;          // (16, 2048, 4096)
    float* out_scores = out_attn + (size_t)NH * L_Q * KV_TOT;   // (16, 2048, 4096)

    // ---- workspace layout (f32 region then bf16 region), ~53 MB
    float* wf     = (float*)d_ws;
    float* ws_qf  = wf;                               // 2048*512
    float* ws_kf  = ws_qf + (size_t)L_Q * HDh;        // 4096*512
    float* ws_vf  = ws_kf + (size_t)KV_TOT * HDh;     // 4096*512
    float* ws_isu = ws_vf + (size_t)KV_TOT * HDh;     // 16*2048
    float* ws_is2 = ws_isu + (size_t)NH * L_Q;        // 16*2048
    short* wsb      = (short*)(ws_is2 + (size_t)NH * L_Q);
    short* x_bf     = wsb;                              // 2048*2048
    short* z_bf     = x_bf + (size_t)L_Q * DIM;         // 4096*512
    short* q_bf     = z_bf + (size_t)KV_TOT * D_KV;     // 2048*512
    short* k_bf     = q_bf + (size_t)L_Q * HDh;         // 4096*512
    short* Vt       = k_bf + (size_t)KV_TOT * HDh;      // 16*32*4096
    short* heads_bf = Vt + (size_t)NH * DH * KV_TOT;    // 2048*512
    short* Wt_lat   = heads_bf + (size_t)L_Q * HDh;     // 512*2048
    short* Wt_q     = Wt_lat + (size_t)D_KV * DIM;      // 512*2048
    short* Wt_k     = Wt_q + (size_t)HDh * DIM;         // 512*512
    short* Wt_v     = Wt_k + (size_t)HDh * D_KV;        // 512*512
    short* Wt_o     = Wt_v + (size_t)HDh * D_KV;        // 2048*512

    // ---- prep: conversions / transposes
    cvt_bf16<<<(L_Q * DIM / 8 + 255) / 256, 256, 0, stream>>>(x, x_bf, L_Q * DIM / 8);
    cvt_bf16<<<(KV_PREV * D_KV / 8 + 255) / 256, 256, 0, stream>>>(
        z_cache, z_bf, KV_PREV * D_KV / 8);
    tr_cvt<<<dim3(DIM / 32, D_KV / 32), 256, 0, stream>>>(W_lat, Wt_lat, DIM, D_KV);
    tr_cvt<<<dim3(DIM / 32, HDh / 32), 256, 0, stream>>>(W_q, Wt_q, DIM, HDh);
    tr_cvt<<<dim3(D_KV / 32, HDh / 32), 256, 0, stream>>>(W_k, Wt_k, D_KV, HDh);
    tr_cvt<<<dim3(D_KV / 32, HDh / 32), 256, 0, stream>>>(W_v, Wt_v, D_KV, HDh);
    tr_cvt<<<dim3(HDh / 32, DIM / 32), 256, 0, stream>>>(W_o, Wt_o, HDh, DIM);

    // ---- z = concat(z_cache, x @ W_latent + b_latent), dual f32+bf16 write
    copy_f4<<<512, 256, 0, stream>>>(z_cache, out_z, (size_t)KV_PREV * D_KV / 4);
    gemm_bf16<<<dim3(D_KV / 64, L_Q / 64), 256, 0, stream>>>(
        x_bf, Wt_lat, b_lat, out_z + (size_t)KV_PREV * D_KV,
        z_bf + (size_t)KV_PREV * D_KV, L_Q, D_KV, DIM);

    // ---- projections + rope + V transpose
    gemm_bf16<<<dim3(HDh / 64, L_Q / 64), 256, 0, stream>>>(
        x_bf, Wt_q, b_q, ws_qf, nullptr, L_Q, HDh, DIM);
    rope_cvt<<<(L_Q * 256) / 256, 256, 0, stream>>>(ws_qf, q_bf, L_Q);
    gemm_bf16<<<dim3(HDh / 64, KV_TOT / 64), 256, 0, stream>>>(
        z_bf, Wt_k, b_k, ws_kf, nullptr, KV_TOT, HDh, D_KV);
    rope_cvt<<<(KV_TOT * 256) / 256, 256, 0, stream>>>(ws_kf, k_bf, KV_TOT);
    gemm_bf16<<<dim3(HDh / 64, KV_TOT / 64), 256, 0, stream>>>(
        z_bf, Wt_v, b_v, ws_vf, nullptr, KV_TOT, HDh, D_KV);
    vt_cvt<<<dim3(KV_TOT / 64, NH), 256, 0, stream>>>(ws_vf, Vt);

    // ---- K1: scores + softmax sums
    scores_stats<<<dim3(L_Q / 64, NH), 256, 0, stream>>>(
        q_bf, k_bf, vlens, out_scores, ws_isu, ws_is2);

    // ---- K2: attn weights (recomputed scores) + PV
    attn_pv<<<dim3(L_Q / 64, NH), 256, 0, stream>>>(
        q_bf, k_bf, vlens, ws_isu, ws_is2, Vt, out_attn, heads_bf);

    // ---- output projection
    gemm_bf16<<<dim3(DIM / 64, L_Q / 64), 256, 0, stream>>>(
        heads_bf, Wt_o, b_o, out_output, nullptr, L_Q, DIM, HDh);
}

// Round 4
// 696.325 us; speedup vs baseline: 1.7933x; 1.0410x over previous
//
#include <hip/hip_runtime.h>
#include <math.h>

// Problem constants (B=1)
#define L_Q     2048
#define KV_PREV 2048
#define KV_TOT  4096
#define DIM     2048
#define D_KV    512
#define NH      16
#define DH      32
#define HDh     512   // NH*DH

typedef short bf16x8 __attribute__((ext_vector_type(8)));
typedef short bf16x4 __attribute__((ext_vector_type(4)));
typedef float f32x4  __attribute__((ext_vector_type(4)));

__device__ inline short f2bf(float f) {   // RNE float -> bf16 bits
    unsigned u = __float_as_uint(f);
    u += 0x7fff + ((u >> 16) & 1);
    return (short)(u >> 16);
}

// inv_freq[j] = 10000^(-j/16) = 10^(-j/4), precomputed in double.
__device__ __constant__ double c_invfreq[16] = {
    1.0, 0.5623413251903491, 0.31622776601683794, 0.17782794100389228,
    0.1, 0.05623413251903491, 0.03162277660168379, 0.017782794100389228,
    0.01, 0.005623413251903491, 0.0031622776601683794, 0.0017782794100389228,
    0.001, 0.0005623413251903491, 0.00031622776601683794, 0.00017782794100389227,
};

// ---------------------------------------------------------------- utilities
__global__ void cvt_bf16(const float* __restrict__ in, short* __restrict__ out, int n8) {
    int i = blockIdx.x * blockDim.x + threadIdx.x;
    if (i >= n8) return;
    float4 a = reinterpret_cast<const float4*>(in)[2 * i];
    float4 b = reinterpret_cast<const float4*>(in)[2 * i + 1];
    union { short s[8]; int4 v; } u;
    u.s[0] = f2bf(a.x); u.s[1] = f2bf(a.y); u.s[2] = f2bf(a.z); u.s[3] = f2bf(a.w);
    u.s[4] = f2bf(b.x); u.s[5] = f2bf(b.y); u.s[6] = f2bf(b.z); u.s[7] = f2bf(b.w);
    reinterpret_cast<int4*>(out)[i] = u.v;
}

// copy f32 -> f32 AND convert to bf16 in one read
__global__ void cvt_copy(const float* __restrict__ src, float* __restrict__ dst,
                         short* __restrict__ dbf, int n8) {
    int i = blockIdx.x * blockDim.x + threadIdx.x;
    if (i >= n8) return;
    float4 a = reinterpret_cast<const float4*>(src)[2 * i];
    float4 b = reinterpret_cast<const float4*>(src)[2 * i + 1];
    reinterpret_cast<float4*>(dst)[2 * i]     = a;
    reinterpret_cast<float4*>(dst)[2 * i + 1] = b;
    union { short s[8]; int4 v; } u;
    u.s[0] = f2bf(a.x); u.s[1] = f2bf(a.y); u.s[2] = f2bf(a.z); u.s[3] = f2bf(a.w);
    u.s[4] = f2bf(b.x); u.s[5] = f2bf(b.y); u.s[6] = f2bf(b.z); u.s[7] = f2bf(b.w);
    reinterpret_cast<int4*>(dbf)[i] = u.v;
}

// in: [K][N] f32 row-major -> out: [N][K] bf16 (transposed weight)
__global__ __launch_bounds__(256) void tr_cvt(const float* __restrict__ in,
        short* __restrict__ out, int K, int N) {
    __shared__ float tile[32][33];
    int k0 = blockIdx.x * 32, n0 = blockIdx.y * 32;
    int c = threadIdx.x & 31, r0 = threadIdx.x >> 5;
    for (int r = r0; r < 32; r += 8)
        tile[r][c] = in[(size_t)(k0 + r) * N + n0 + c];
    __syncthreads();
    for (int r = r0; r < 32; r += 8)
        out[(size_t)(n0 + r) * K + k0 + c] = f2bf(tile[c][r]);
}

// v_bf: [KV][512] bf16 -> Vt: [NH][32][KV] bf16 (per-head transposed V)
__global__ __launch_bounds__(256) void vt_cvt(const short* __restrict__ v, short* __restrict__ vt) {
    __shared__ short tile[64][34];
    int h = blockIdx.y, kv0 = blockIdx.x * 64;
    int c = threadIdx.x & 31, r0 = threadIdx.x >> 5;
    for (int r = r0; r < 64; r += 8)
        tile[r][c] = v[(size_t)(kv0 + r) * HDh + h * DH + c];
    __syncthreads();
    int l = threadIdx.x & 63, wv = threadIdx.x >> 6;
    for (int d = wv; d < 32; d += 4)
        vt[((size_t)h * DH + d) * KV_TOT + kv0 + l] = tile[l][d];
}

// ------------------------------------------------- bf16 MFMA projection GEMM
// C(MxN) f32 = A(MxK) bf16 @ Bt(NxK) bf16^T + bias. Block 64x64, 4 waves.
// C (f32) optional; Cbf (bf16 mirror) optional; ROPE: apply rotary to the
// biased result and write ONLY Cbf (layout [M][H][32], pairs (c, c+16), freq
// index = c&15, position = row).
__global__ __launch_bounds__(256) void gemm_bf16(const short* __restrict__ A,
        const short* __restrict__ Bt, const float* __restrict__ bias,
        float* __restrict__ C, short* __restrict__ Cbf, int rope,
        int M, int N, int K)
{
    int t = threadIdx.x, w = t >> 6, l = t & 63, lr = l & 15, lg = l >> 4;
    int m0 = blockIdx.y * 64 + w * 16;
    int n0 = blockIdx.x * 64;
    f32x4 acc[4] = {{0,0,0,0},{0,0,0,0},{0,0,0,0},{0,0,0,0}};
    const short* ap  = A  + (size_t)(m0 + lr) * K + lg * 8;
    const short* bp0 = Bt + (size_t)(n0 + lr) * K + lg * 8;
    #pragma unroll 2
    for (int k0 = 0; k0 < K; k0 += 32) {
        bf16x8 a = *reinterpret_cast<const bf16x8*>(ap + k0);
        #pragma unroll
        for (int j = 0; j < 4; ++j) {
            bf16x8 b = *reinterpret_cast<const bf16x8*>(bp0 + (size_t)j * 16 * K + k0);
            acc[j] = __builtin_amdgcn_mfma_f32_16x16x32_bf16(a, b, acc[j], 0, 0, 0);
        }
    }
    float bs[4];
    #pragma unroll
    for (int j = 0; j < 4; ++j) bs[j] = bias[n0 + j * 16 + lr];

    if (rope) {
        // pairs: (acc[0],acc[1]) = head at n0/32, (acc[2],acc[3]) = next head
        #pragma unroll
        for (int r = 0; r < 4; ++r) {
            int m = m0 + lg * 4 + r;
            float ang = (float)((double)m * c_invfreq[lr]);
            float cs = cosf(ang), sn = sinf(ang);
            size_t rb = (size_t)m * N + n0 + lr;
            float a1 = acc[0][r] + bs[0], a2 = acc[1][r] + bs[1];
            Cbf[rb]      = f2bf(a1 * cs - a2 * sn);
            Cbf[rb + 16] = f2bf(a1 * sn + a2 * cs);
            float b1 = acc[2][r] + bs[2], b2 = acc[3][r] + bs[3];
            Cbf[rb + 32] = f2bf(b1 * cs - b2 * sn);
            Cbf[rb + 48] = f2bf(b1 * sn + b2 * cs);
        }
        return;
    }
    #pragma unroll
    for (int j = 0; j < 4; ++j) {
        int n = n0 + j * 16 + lr;
        #pragma unroll
        for (int r = 0; r < 4; ++r) {
            float v = acc[j][r] + bs[j];
            size_t idx = (size_t)(m0 + lg * 4 + r) * N + n;
            if (C)   C[idx] = v;
            if (Cbf) Cbf[idx] = f2bf(v);
        }
    }
}

// ---------------------------------------- K1: scores + online softmax sums
// SWAPPED operands: D[k][q] -> each lane owns 4 consecutive k of ONE q row.
// Scores stored as aligned f32x4 nontemporal. K-tile loads software-pipelined
// (issued before stores so waitcnt never drains the store queue).
__global__ __launch_bounds__(256) void scores_stats(const short* __restrict__ q,
        const short* __restrict__ kmat, const int* __restrict__ vlens,
        float* __restrict__ scores, float* __restrict__ isu_o, float* __restrict__ is2_o)
{
    int t = threadIdx.x, w = t >> 6, l = t & 63, lr = l & 15, lg = l >> 4;
    int h = blockIdx.y;
    int qrow = blockIdx.x * 64 + w * 16;
    int myq = qrow + lr;
    bf16x8 bQ = *reinterpret_cast<const bf16x8*>(q + (size_t)myq * HDh + h * DH + lg * 8);
    int vl = vlens[myq];
    const short* kp = kmat + h * DH + lg * 8;
    float* sp = scores + ((size_t)h * L_Q + myq) * KV_TOT;
    const float sc = 0.17677669529663687f;  // 1/sqrt(32)
    float su = 0.f, s2 = 0.f;
    const int kb = lg * 4;   // reg r -> k = k0 + kb + r (tile0), +16 (tile1)

    bf16x8 a0 = *reinterpret_cast<const bf16x8*>(kp + (size_t)lr * HDh);
    bf16x8 a1 = *reinterpret_cast<const bf16x8*>(kp + (size_t)(16 + lr) * HDh);
    for (int k0 = 0; k0 < KV_TOT; k0 += 32) {
        int kn = (k0 + 32) & (KV_TOT - 1);
        bf16x8 a0n = *reinterpret_cast<const bf16x8*>(kp + (size_t)(kn + lr) * HDh);
        bf16x8 a1n = *reinterpret_cast<const bf16x8*>(kp + (size_t)(kn + 16 + lr) * HDh);
        f32x4 z4 = {0.f, 0.f, 0.f, 0.f};
        f32x4 s0 = __builtin_amdgcn_mfma_f32_16x16x32_bf16(a0, bQ, z4, 0, 0, 0);
        f32x4 s1 = __builtin_amdgcn_mfma_f32_16x16x32_bf16(a1, bQ, z4, 0, 0, 0);
        f32x4 o0, o1;
        #pragma unroll
        for (int r = 0; r < 4; ++r) { o0[r] = s0[r] * sc; o1[r] = s1[r] * sc; }
        __builtin_nontemporal_store(o0, reinterpret_cast<f32x4*>(sp + k0 + kb));
        __builtin_nontemporal_store(o1, reinterpret_cast<f32x4*>(sp + k0 + 16 + kb));
        #pragma unroll
        for (int r = 0; r < 4; ++r) {
            float e0 = __expf(o0[r]), e1 = __expf(o1[r]);
            su += e0 + e1;
            if (k0 + kb + r < vl)      s2 += e0;
            if (k0 + 16 + kb + r < vl) s2 += e1;
        }
        a0 = a0n; a1 = a1n;
    }
    su += __shfl_xor(su, 16, 64); su += __shfl_xor(su, 32, 64);
    s2 += __shfl_xor(s2, 16, 64); s2 += __shfl_xor(s2, 32, 64);
    if (lg == 0) {
        size_t idx = (size_t)h * L_Q + myq;
        isu_o[idx] = 1.f / su;
        is2_o[idx] = 1.f / s2;
    }
}

// --------------------- K2: recompute scores, write attn, masked PV (MFMA)
// Same swapped layout. attn as f32x4 nt stores. P staged per-wave in LDS
// ([q=16][k=64], pad 72) via ds_write_b64, read back as A-fragments (row=q).
__global__ __launch_bounds__(256) void attn_pv(const short* __restrict__ q,
        const short* __restrict__ kmat, const int* __restrict__ vlens,
        const float* __restrict__ isu_i, const float* __restrict__ is2_i,
        const short* __restrict__ Vt,
        float* __restrict__ attn, short* __restrict__ heads_bf)
{
    __shared__ short Plds[4][16][72];
    int t = threadIdx.x, w = t >> 6, l = t & 63, lr = l & 15, lg = l >> 4;
    int h = blockIdx.y;
    int qrow = blockIdx.x * 64 + w * 16;
    int myq = qrow + lr;
    bf16x8 bQ = *reinterpret_cast<const bf16x8*>(q + (size_t)myq * HDh + h * DH + lg * 8);
    int vl = vlens[myq];
    size_t sidx = (size_t)h * L_Q + myq;
    float isu = isu_i[sidx], is2 = is2_i[sidx];
    float* ap_ = attn + sidx * KV_TOT;
    const short* kp  = kmat + h * DH + lg * 8;
    const short* vp0 = Vt + ((size_t)h * DH + lr) * KV_TOT + lg * 8;   // d = lr
    const short* vp1 = vp0 + (size_t)16 * KV_TOT;                      // d = 16+lr
    const float sc = 0.17677669529663687f;
    short* prow = &Plds[w][lr][0];
    f32x4 h0 = {0,0,0,0}, h1 = {0,0,0,0};

    for (int k0 = 0; k0 < KV_TOT; k0 += 64) {
        #pragma unroll
        for (int kt = 0; kt < 4; ++kt) {
            int kk = k0 + kt * 16;
            bf16x8 aK = *reinterpret_cast<const bf16x8*>(kp + (size_t)(kk + lr) * HDh);
            f32x4 z4 = {0.f, 0.f, 0.f, 0.f};
            f32x4 s = __builtin_amdgcn_mfma_f32_16x16x32_bf16(aK, bQ, z4, 0, 0, 0);
            f32x4 oa;
            bf16x4 pb;
            #pragma unroll
            for (int r = 0; r < 4; ++r) {
                float e = __expf(s[r] * sc);
                oa[r] = e * isu;
                pb[r] = (kk + lg * 4 + r < vl) ? f2bf(e * is2) : (short)0;
            }
            __builtin_nontemporal_store(oa, reinterpret_cast<f32x4*>(ap_ + kk + lg * 4));
            *reinterpret_cast<bf16x4*>(prow + kt * 16 + lg * 4) = pb;
        }
        #pragma unroll
        for (int kbl = 0; kbl < 2; ++kbl) {
            bf16x8 pa = *reinterpret_cast<const bf16x8*>(prow + kbl * 32 + lg * 8);
            bf16x8 b0 = *reinterpret_cast<const bf16x8*>(vp0 + k0 + kbl * 32);
            bf16x8 b1 = *reinterpret_cast<const bf16x8*>(vp1 + k0 + kbl * 32);
            h0 = __builtin_amdgcn_mfma_f32_16x16x32_bf16(pa, b0, h0, 0, 0, 0);
            h1 = __builtin_amdgcn_mfma_f32_16x16x32_bf16(pa, b1, h1, 0, 0, 0);
        }
    }
    // D[q][d]: col = d = lr, row = q = lg*4 + r
    #pragma unroll
    for (int r = 0; r < 4; ++r) {
        size_t ho = (size_t)(qrow + lg * 4 + r) * HDh + h * DH + lr;
        heads_bf[ho]      = f2bf(h0[r]);
        heads_bf[ho + 16] = f2bf(h1[r]);
    }
}

// ------------------------------------------------------------------ launch
extern "C" void kernel_launch(void* const* d_in, const int* in_sizes, int n_in,
                              void* d_out, int out_size, void* d_ws, size_t ws_size,
                              hipStream_t stream) {
    const float* x       = (const float*)d_in[0];
    const float* z_cache = (const float*)d_in[1];
    const int*   vlens   = (const int*)  d_in[2];
    const float* W_lat   = (const float*)d_in[3];
    const float* b_lat   = (const float*)d_in[4];
    const float* W_q     = (const float*)d_in[5];
    const float* b_q     = (const float*)d_in[6];
    const float* W_k     = (const float*)d_in[7];
    const float* b_k     = (const float*)d_in[8];
    const float* W_v     = (const float*)d_in[9];
    const float* b_v     = (const float*)d_in[10];
    const float* W_o     = (const float*)d_in[11];
    const float* b_o     = (const float*)d_in[12];

    float* out        = (float*)d_out;
    float* out_output = out;                                    // (2048, 2048)
    float* out_z      = out_output + (size_t)L_Q * DIM;         // (4096, 512)
    float* out_attn   = out_z + (size_t)KV_TOT * D_KV;          // (16, 2048, 4096)
    float* out_scores = out_attn + (size_t)NH * L_Q * KV_TOT;   // (16, 2048, 4096)

    // ---- workspace layout
    float* wf     = (float*)d_ws;
    float* ws_isu = wf;                               // 16*2048
    float* ws_is2 = ws_isu + (size_t)NH * L_Q;        // 16*2048
    short* wsb      = (short*)(ws_is2 + (size_t)NH * L_Q);
    short* x_bf     = wsb;                              // 2048*2048
    short* z_bf     = x_bf + (size_t)L_Q * DIM;         // 4096*512
    short* q_bf     = z_bf + (size_t)KV_TOT * D_KV;     // 2048*512
    short* k_bf     = q_bf + (size_t)L_Q * HDh;         // 4096*512
    short* v_bf     = k_bf + (size_t)KV_TOT * HDh;      // 4096*512
    short* Vt       = v_bf + (size_t)KV_TOT * HDh;      // 16*32*4096
    short* heads_bf = Vt + (size_t)NH * DH * KV_TOT;    // 2048*512
    short* Wt_lat   = heads_bf + (size_t)L_Q * HDh;     // 512*2048
    short* Wt_q     = Wt_lat + (size_t)D_KV * DIM;      // 512*2048
    short* Wt_k     = Wt_q + (size_t)HDh * DIM;         // 512*512
    short* Wt_v     = Wt_k + (size_t)HDh * D_KV;        // 512*512
    short* Wt_o     = Wt_v + (size_t)HDh * D_KV;        // 2048*512

    // ---- prep: conversions / transposes
    cvt_bf16<<<(L_Q * DIM / 8 + 255) / 256, 256, 0, stream>>>(x, x_bf, L_Q * DIM / 8);
    cvt_copy<<<(KV_PREV * D_KV / 8 + 255) / 256, 256, 0, stream>>>(
        z_cache, out_z, z_bf, KV_PREV * D_KV / 8);
    tr_cvt<<<dim3(DIM / 32, D_KV / 32), 256, 0, stream>>>(W_lat, Wt_lat, DIM, D_KV);
    tr_cvt<<<dim3(DIM / 32, HDh / 32), 256, 0, stream>>>(W_q, Wt_q, DIM, HDh);
    tr_cvt<<<dim3(D_KV / 32, HDh / 32), 256, 0, stream>>>(W_k, Wt_k, D_KV, HDh);
    tr_cvt<<<dim3(D_KV / 32, HDh / 32), 256, 0, stream>>>(W_v, Wt_v, D_KV, HDh);
    tr_cvt<<<dim3(HDh / 32, DIM / 32), 256, 0, stream>>>(W_o, Wt_o, HDh, DIM);

    // ---- z = concat(z_cache, x @ W_latent + b_latent), dual f32+bf16 write
    gemm_bf16<<<dim3(D_KV / 64, L_Q / 64), 256, 0, stream>>>(
        x_bf, Wt_lat, b_lat, out_z + (size_t)KV_PREV * D_KV,
        z_bf + (size_t)KV_PREV * D_KV, 0, L_Q, D_KV, DIM);

    // ---- projections (rope fused into q/k epilogues; v direct bf16)
    gemm_bf16<<<dim3(HDh / 64, L_Q / 64), 256, 0, stream>>>(
        x_bf, Wt_q, b_q, nullptr, q_bf, 1, L_Q, HDh, DIM);
    gemm_bf16<<<dim3(HDh / 64, KV_TOT / 64), 256, 0, stream>>>(
        z_bf, Wt_k, b_k, nullptr, k_bf, 1, KV_TOT, HDh, D_KV);
    gemm_bf16<<<dim3(HDh / 64, KV_TOT / 64), 256, 0, stream>>>(
        z_bf, Wt_v, b_v, nullptr, v_bf, 0, KV_TOT, HDh, D_KV);
    vt_cvt<<<dim3(KV_TOT / 64, NH), 256, 0, stream>>>(v_bf, Vt);

    // ---- K1: scores + softmax sums
    scores_stats<<<dim3(L_Q / 64, NH), 256, 0, stream>>>(
        q_bf, k_bf, vlens, out_scores, ws_isu, ws_is2);

    // ---- K2: attn weights (recomputed scores) + PV
    attn_pv<<<dim3(L_Q / 64, NH), 256, 0, stream>>>(
        q_bf, k_bf, vlens, ws_isu, ws_is2, Vt, out_attn, heads_bf);

    // ---- output projection
    gemm_bf16<<<dim3(DIM / 64, L_Q / 64), 256, 0, stream>>>(
        heads_bf, Wt_o, b_o, out_output, nullptr, 0, L_Q, DIM, HDh);
}

// Round 5
// 560.137 us; speedup vs baseline: 2.2293x; 1.2431x over previous
//
#include <hip/hip_runtime.h>
#include <math.h>

// Problem constants (B=1)
#define L_Q     2048
#define KV_PREV 2048
#define KV_TOT  4096
#define DIM     2048
#define D_KV    512
#define NH      16
#define DH      32
#define HDh     512   // NH*DH
#define KC      256   // k-chunk staged in LDS before contiguous writeout

typedef short bf16x8 __attribute__((ext_vector_type(8)));
typedef short bf16x4 __attribute__((ext_vector_type(4)));
typedef float f32x4  __attribute__((ext_vector_type(4)));

__device__ inline short f2bf(float f) {   // RNE float -> bf16 bits
    unsigned u = __float_as_uint(f);
    u += 0x7fff + ((u >> 16) & 1);
    return (short)(u >> 16);
}

// inv_freq[j] = 10000^(-j/16) = 10^(-j/4), precomputed in double.
__device__ __constant__ double c_invfreq[16] = {
    1.0, 0.5623413251903491, 0.31622776601683794, 0.17782794100389228,
    0.1, 0.05623413251903491, 0.03162277660168379, 0.017782794100389228,
    0.01, 0.005623413251903491, 0.0031622776601683794, 0.0017782794100389228,
    0.001, 0.0005623413251903491, 0.00031622776601683794, 0.00017782794100389227,
};

// ---------------------------------------------------------------- utilities
__global__ void cvt_bf16(const float* __restrict__ in, short* __restrict__ out, int n8) {
    int i = blockIdx.x * blockDim.x + threadIdx.x;
    if (i >= n8) return;
    float4 a = reinterpret_cast<const float4*>(in)[2 * i];
    float4 b = reinterpret_cast<const float4*>(in)[2 * i + 1];
    union { short s[8]; int4 v; } u;
    u.s[0] = f2bf(a.x); u.s[1] = f2bf(a.y); u.s[2] = f2bf(a.z); u.s[3] = f2bf(a.w);
    u.s[4] = f2bf(b.x); u.s[5] = f2bf(b.y); u.s[6] = f2bf(b.z); u.s[7] = f2bf(b.w);
    reinterpret_cast<int4*>(out)[i] = u.v;
}

// copy f32 -> f32 AND convert to bf16 in one read
__global__ void cvt_copy(const float* __restrict__ src, float* __restrict__ dst,
                         short* __restrict__ dbf, int n8) {
    int i = blockIdx.x * blockDim.x + threadIdx.x;
    if (i >= n8) return;
    float4 a = reinterpret_cast<const float4*>(src)[2 * i];
    float4 b = reinterpret_cast<const float4*>(src)[2 * i + 1];
    reinterpret_cast<float4*>(dst)[2 * i]     = a;
    reinterpret_cast<float4*>(dst)[2 * i + 1] = b;
    union { short s[8]; int4 v; } u;
    u.s[0] = f2bf(a.x); u.s[1] = f2bf(a.y); u.s[2] = f2bf(a.z); u.s[3] = f2bf(a.w);
    u.s[4] = f2bf(b.x); u.s[5] = f2bf(b.y); u.s[6] = f2bf(b.z); u.s[7] = f2bf(b.w);
    reinterpret_cast<int4*>(dbf)[i] = u.v;
}

// in: [K][N] f32 row-major -> out: [N][K] bf16 (transposed weight)
__global__ __launch_bounds__(256) void tr_cvt(const float* __restrict__ in,
        short* __restrict__ out, int K, int N) {
    __shared__ float tile[32][33];
    int k0 = blockIdx.x * 32, n0 = blockIdx.y * 32;
    int c = threadIdx.x & 31, r0 = threadIdx.x >> 5;
    for (int r = r0; r < 32; r += 8)
        tile[r][c] = in[(size_t)(k0 + r) * N + n0 + c];
    __syncthreads();
    for (int r = r0; r < 32; r += 8)
        out[(size_t)(n0 + r) * K + k0 + c] = f2bf(tile[c][r]);
}

// v_bf: [KV][512] bf16 -> Vt: [NH][32][KV] bf16 (per-head transposed V)
__global__ __launch_bounds__(256) void vt_cvt(const short* __restrict__ v, short* __restrict__ vt) {
    __shared__ short tile[64][34];
    int h = blockIdx.y, kv0 = blockIdx.x * 64;
    int c = threadIdx.x & 31, r0 = threadIdx.x >> 5;
    for (int r = r0; r < 64; r += 8)
        tile[r][c] = v[(size_t)(kv0 + r) * HDh + h * DH + c];
    __syncthreads();
    int l = threadIdx.x & 63, wv = threadIdx.x >> 6;
    for (int d = wv; d < 32; d += 4)
        vt[((size_t)h * DH + d) * KV_TOT + kv0 + l] = tile[l][d];
}

// ------------------------------------------------- bf16 MFMA projection GEMM
__global__ __launch_bounds__(256) void gemm_bf16(const short* __restrict__ A,
        const short* __restrict__ Bt, const float* __restrict__ bias,
        float* __restrict__ C, short* __restrict__ Cbf, int rope,
        int M, int N, int K)
{
    int t = threadIdx.x, w = t >> 6, l = t & 63, lr = l & 15, lg = l >> 4;
    int m0 = blockIdx.y * 64 + w * 16;
    int n0 = blockIdx.x * 64;
    f32x4 acc[4] = {{0,0,0,0},{0,0,0,0},{0,0,0,0},{0,0,0,0}};
    const short* ap  = A  + (size_t)(m0 + lr) * K + lg * 8;
    const short* bp0 = Bt + (size_t)(n0 + lr) * K + lg * 8;
    #pragma unroll 2
    for (int k0 = 0; k0 < K; k0 += 32) {
        bf16x8 a = *reinterpret_cast<const bf16x8*>(ap + k0);
        #pragma unroll
        for (int j = 0; j < 4; ++j) {
            bf16x8 b = *reinterpret_cast<const bf16x8*>(bp0 + (size_t)j * 16 * K + k0);
            acc[j] = __builtin_amdgcn_mfma_f32_16x16x32_bf16(a, b, acc[j], 0, 0, 0);
        }
    }
    float bs[4];
    #pragma unroll
    for (int j = 0; j < 4; ++j) bs[j] = bias[n0 + j * 16 + lr];

    if (rope) {
        #pragma unroll
        for (int r = 0; r < 4; ++r) {
            int m = m0 + lg * 4 + r;
            float ang = (float)((double)m * c_invfreq[lr]);
            float cs = cosf(ang), sn = sinf(ang);
            size_t rb = (size_t)m * N + n0 + lr;
            float a1 = acc[0][r] + bs[0], a2 = acc[1][r] + bs[1];
            Cbf[rb]      = f2bf(a1 * cs - a2 * sn);
            Cbf[rb + 16] = f2bf(a1 * sn + a2 * cs);
            float b1 = acc[2][r] + bs[2], b2 = acc[3][r] + bs[3];
            Cbf[rb + 32] = f2bf(b1 * cs - b2 * sn);
            Cbf[rb + 48] = f2bf(b1 * sn + b2 * cs);
        }
        return;
    }
    #pragma unroll
    for (int j = 0; j < 4; ++j) {
        int n = n0 + j * 16 + lr;
        #pragma unroll
        for (int r = 0; r < 4; ++r) {
            float v = acc[j][r] + bs[j];
            size_t idx = (size_t)(m0 + lg * 4 + r) * N + n;
            if (C)   C[idx] = v;
            if (Cbf) Cbf[idx] = f2bf(v);
        }
    }
}

// ---------------------------------------- K1: scores + online softmax sums
// Swapped-operand QK^T (D[k][q]); 16x256 f32 tiles staged in WAVE-PRIVATE LDS,
// then written out with 64 lanes on one row per instruction (1 KB contiguous
// bursts) for DRAM row locality. Sums accumulated from registers.
__global__ __launch_bounds__(256) void scores_stats(const short* __restrict__ q,
        const short* __restrict__ kmat, const int* __restrict__ vlens,
        float* __restrict__ scores, float* __restrict__ isu_o, float* __restrict__ is2_o)
{
    __shared__ float Sl[4][16][KC + 4];   // 66.6 KB, wave-private tiles
    int t = threadIdx.x, w = t >> 6, l = t & 63, lr = l & 15, lg = l >> 4;
    int h = blockIdx.y;
    int qrow = blockIdx.x * 64 + w * 16;
    int myq = qrow + lr;
    bf16x8 bQ = *reinterpret_cast<const bf16x8*>(q + (size_t)myq * HDh + h * DH + lg * 8);
    int vl = vlens[myq];
    const short* kp = kmat + h * DH + lg * 8;
    const float sc = 0.17677669529663687f;  // 1/sqrt(32)
    float su = 0.f, s2 = 0.f;
    const int kb = lg * 4;

    bf16x8 a0 = *reinterpret_cast<const bf16x8*>(kp + (size_t)lr * HDh);
    bf16x8 a1 = *reinterpret_cast<const bf16x8*>(kp + (size_t)(16 + lr) * HDh);
    for (int c = 0; c < KV_TOT / KC; ++c) {
        #pragma unroll
        for (int kt = 0; kt < KC / 32; ++kt) {
            int k0 = c * KC + kt * 32;
            int kn = (k0 + 32) & (KV_TOT - 1);
            bf16x8 a0n = *reinterpret_cast<const bf16x8*>(kp + (size_t)(kn + lr) * HDh);
            bf16x8 a1n = *reinterpret_cast<const bf16x8*>(kp + (size_t)(kn + 16 + lr) * HDh);
            f32x4 z4 = {0.f, 0.f, 0.f, 0.f};
            f32x4 s0 = __builtin_amdgcn_mfma_f32_16x16x32_bf16(a0, bQ, z4, 0, 0, 0);
            f32x4 s1 = __builtin_amdgcn_mfma_f32_16x16x32_bf16(a1, bQ, z4, 0, 0, 0);
            f32x4 o0, o1;
            #pragma unroll
            for (int r = 0; r < 4; ++r) { o0[r] = s0[r] * sc; o1[r] = s1[r] * sc; }
            *reinterpret_cast<f32x4*>(&Sl[w][lr][kt * 32 + kb])      = o0;
            *reinterpret_cast<f32x4*>(&Sl[w][lr][kt * 32 + 16 + kb]) = o1;
            #pragma unroll
            for (int r = 0; r < 4; ++r) {
                float e0 = __expf(o0[r]), e1 = __expf(o1[r]);
                su += e0 + e1;
                if (k0 + kb + r < vl)      s2 += e0;
                if (k0 + 16 + kb + r < vl) s2 += e1;
            }
            a0 = a0n; a1 = a1n;
        }
        // wave-private writeout: one row per instruction, 1 KB contiguous
        #pragma unroll
        for (int r = 0; r < 16; ++r) {
            f32x4 v = *reinterpret_cast<const f32x4*>(&Sl[w][r][l * 4]);
            float* dst = scores + ((size_t)h * L_Q + qrow + r) * KV_TOT + c * KC + l * 4;
            __builtin_nontemporal_store(v, reinterpret_cast<f32x4*>(dst));
        }
    }
    su += __shfl_xor(su, 16, 64); su += __shfl_xor(su, 32, 64);
    s2 += __shfl_xor(s2, 16, 64); s2 += __shfl_xor(s2, 32, 64);
    if (lg == 0) {
        size_t idx = (size_t)h * L_Q + myq;
        isu_o[idx] = 1.f / su;
        is2_o[idx] = 1.f / s2;
    }
}

// --------------------- K2: recompute scores, write attn, masked PV (MFMA)
// Same LDS-staged contiguous writeout for attn; P staged per-wave for PV.
__global__ __launch_bounds__(256) void attn_pv(const short* __restrict__ q,
        const short* __restrict__ kmat, const int* __restrict__ vlens,
        const float* __restrict__ isu_i, const float* __restrict__ is2_i,
        const short* __restrict__ Vt,
        float* __restrict__ attn, short* __restrict__ heads_bf)
{
    __shared__ float Al[4][16][KC + 4];   // 66.6 KB
    __shared__ short Plds[4][16][72];     //  9.2 KB
    int t = threadIdx.x, w = t >> 6, l = t & 63, lr = l & 15, lg = l >> 4;
    int h = blockIdx.y;
    int qrow = blockIdx.x * 64 + w * 16;
    int myq = qrow + lr;
    bf16x8 bQ = *reinterpret_cast<const bf16x8*>(q + (size_t)myq * HDh + h * DH + lg * 8);
    int vl = vlens[myq];
    size_t sidx = (size_t)h * L_Q + myq;
    float isu = isu_i[sidx], is2 = is2_i[sidx];
    const short* kp  = kmat + h * DH + lg * 8;
    const short* vp0 = Vt + ((size_t)h * DH + lr) * KV_TOT + lg * 8;   // d = lr
    const short* vp1 = vp0 + (size_t)16 * KV_TOT;                      // d = 16+lr
    const float sc = 0.17677669529663687f;
    short* prow = &Plds[w][lr][0];
    f32x4 h0 = {0,0,0,0}, h1 = {0,0,0,0};

    for (int c = 0; c < KV_TOT / KC; ++c) {
        #pragma unroll
        for (int g = 0; g < KC / 64; ++g) {
            #pragma unroll
            for (int kt = 0; kt < 4; ++kt) {
                int kk = c * KC + g * 64 + kt * 16;
                bf16x8 aK = *reinterpret_cast<const bf16x8*>(kp + (size_t)(kk + lr) * HDh);
                f32x4 z4 = {0.f, 0.f, 0.f, 0.f};
                f32x4 s = __builtin_amdgcn_mfma_f32_16x16x32_bf16(aK, bQ, z4, 0, 0, 0);
                f32x4 oa;
                bf16x4 pb;
                #pragma unroll
                for (int r = 0; r < 4; ++r) {
                    float e = __expf(s[r] * sc);
                    oa[r] = e * isu;
                    pb[r] = (kk + lg * 4 + r < vl) ? f2bf(e * is2) : (short)0;
                }
                *reinterpret_cast<f32x4*>(&Al[w][lr][g * 64 + kt * 16 + lg * 4]) = oa;
                *reinterpret_cast<bf16x4*>(prow + kt * 16 + lg * 4) = pb;
            }
            #pragma unroll
            for (int kbl = 0; kbl < 2; ++kbl) {
                int kv = c * KC + g * 64 + kbl * 32;
                bf16x8 pa = *reinterpret_cast<const bf16x8*>(prow + kbl * 32 + lg * 8);
                bf16x8 b0 = *reinterpret_cast<const bf16x8*>(vp0 + kv);
                bf16x8 b1 = *reinterpret_cast<const bf16x8*>(vp1 + kv);
                h0 = __builtin_amdgcn_mfma_f32_16x16x32_bf16(pa, b0, h0, 0, 0, 0);
                h1 = __builtin_amdgcn_mfma_f32_16x16x32_bf16(pa, b1, h1, 0, 0, 0);
            }
        }
        // wave-private writeout: one row per instruction, 1 KB contiguous
        #pragma unroll
        for (int r = 0; r < 16; ++r) {
            f32x4 v = *reinterpret_cast<const f32x4*>(&Al[w][r][l * 4]);
            float* dst = attn + ((size_t)h * L_Q + qrow + r) * KV_TOT + c * KC + l * 4;
            __builtin_nontemporal_store(v, reinterpret_cast<f32x4*>(dst));
        }
    }
    // D[q][d]: col = d = lr, row = q = lg*4 + r
    #pragma unroll
    for (int r = 0; r < 4; ++r) {
        size_t ho = (size_t)(qrow + lg * 4 + r) * HDh + h * DH + lr;
        heads_bf[ho]      = f2bf(h0[r]);
        heads_bf[ho + 16] = f2bf(h1[r]);
    }
}

// ------------------------------------------------------------------ launch
extern "C" void kernel_launch(void* const* d_in, const int* in_sizes, int n_in,
                              void* d_out, int out_size, void* d_ws, size_t ws_size,
                              hipStream_t stream) {
    const float* x       = (const float*)d_in[0];
    const float* z_cache = (const float*)d_in[1];
    const int*   vlens   = (const int*)  d_in[2];
    const float* W_lat   = (const float*)d_in[3];
    const float* b_lat   = (const float*)d_in[4];
    const float* W_q     = (const float*)d_in[5];
    const float* b_q     = (const float*)d_in[6];
    const float* W_k     = (const float*)d_in[7];
    const float* b_k     = (const float*)d_in[8];
    const float* W_v     = (const float*)d_in[9];
    const float* b_v     = (const float*)d_in[10];
    const float* W_o     = (const float*)d_in[11];
    const float* b_o     = (const float*)d_in[12];

    float* out        = (float*)d_out;
    float* out_output = out;                                    // (2048, 2048)
    float* out_z      = out_output + (size_t)L_Q * DIM;         // (4096, 512)
    float* out_attn   = out_z + (size_t)KV_TOT * D_KV;          // (16, 2048, 4096)
    float* out_scores = out_attn + (size_t)NH * L_Q * KV_TOT;   // (16, 2048, 4096)

    // ---- workspace layout
    float* wf     = (float*)d_ws;
    float* ws_isu = wf;                               // 16*2048
    float* ws_is2 = ws_isu + (size_t)NH * L_Q;        // 16*2048
    short* wsb      = (short*)(ws_is2 + (size_t)NH * L_Q);
    short* x_bf     = wsb;                              // 2048*2048
    short* z_bf     = x_bf + (size_t)L_Q * DIM;         // 4096*512
    short* q_bf     = z_bf + (size_t)KV_TOT * D_KV;     // 2048*512
    short* k_bf     = q_bf + (size_t)L_Q * HDh;         // 4096*512
    short* v_bf     = k_bf + (size_t)KV_TOT * HDh;      // 4096*512
    short* Vt       = v_bf + (size_t)KV_TOT * HDh;      // 16*32*4096
    short* heads_bf = Vt + (size_t)NH * DH * KV_TOT;    // 2048*512
    short* Wt_lat   = heads_bf + (size_t)L_Q * HDh;     // 512*2048
    short* Wt_q     = Wt_lat + (size_t)D_KV * DIM;      // 512*2048
    short* Wt_k     = Wt_q + (size_t)HDh * DIM;         // 512*512
    short* Wt_v     = Wt_k + (size_t)HDh * D_KV;        // 512*512
    short* Wt_o     = Wt_v + (size_t)HDh * D_KV;        // 2048*512

    // ---- prep: conversions / transposes
    cvt_bf16<<<(L_Q * DIM / 8 + 255) / 256, 256, 0, stream>>>(x, x_bf, L_Q * DIM / 8);
    cvt_copy<<<(KV_PREV * D_KV / 8 + 255) / 256, 256, 0, stream>>>(
        z_cache, out_z, z_bf, KV_PREV * D_KV / 8);
    tr_cvt<<<dim3(DIM / 32, D_KV / 32), 256, 0, stream>>>(W_lat, Wt_lat, DIM, D_KV);
    tr_cvt<<<dim3(DIM / 32, HDh / 32), 256, 0, stream>>>(W_q, Wt_q, DIM, HDh);
    tr_cvt<<<dim3(D_KV / 32, HDh / 32), 256, 0, stream>>>(W_k, Wt_k, D_KV, HDh);
    tr_cvt<<<dim3(D_KV / 32, HDh / 32), 256, 0, stream>>>(W_v, Wt_v, D_KV, HDh);
    tr_cvt<<<dim3(HDh / 32, DIM / 32), 256, 0, stream>>>(W_o, Wt_o, HDh, DIM);

    // ---- z = concat(z_cache, x @ W_latent + b_latent), dual f32+bf16 write
    gemm_bf16<<<dim3(D_KV / 64, L_Q / 64), 256, 0, stream>>>(
        x_bf, Wt_lat, b_lat, out_z + (size_t)KV_PREV * D_KV,
        z_bf + (size_t)KV_PREV * D_KV, 0, L_Q, D_KV, DIM);

    // ---- projections (rope fused into q/k epilogues; v direct bf16)
    gemm_bf16<<<dim3(HDh / 64, L_Q / 64), 256, 0, stream>>>(
        x_bf, Wt_q, b_q, nullptr, q_bf, 1, L_Q, HDh, DIM);
    gemm_bf16<<<dim3(HDh / 64, KV_TOT / 64), 256, 0, stream>>>(
        z_bf, Wt_k, b_k, nullptr, k_bf, 1, KV_TOT, HDh, D_KV);
    gemm_bf16<<<dim3(HDh / 64, KV_TOT / 64), 256, 0, stream>>>(
        z_bf, Wt_v, b_v, nullptr, v_bf, 0, KV_TOT, HDh, D_KV);
    vt_cvt<<<dim3(KV_TOT / 64, NH), 256, 0, stream>>>(v_bf, Vt);

    // ---- K1: scores + softmax sums
    scores_stats<<<dim3(L_Q / 64, NH), 256, 0, stream>>>(
        q_bf, k_bf, vlens, out_scores, ws_isu, ws_is2);

    // ---- K2: attn weights (recomputed scores) + PV
    attn_pv<<<dim3(L_Q / 64, NH), 256, 0, stream>>>(
        q_bf, k_bf, vlens, ws_isu, ws_is2, Vt, out_attn, heads_bf);

    // ---- output projection
    gemm_bf16<<<dim3(DIM / 64, L_Q / 64), 256, 0, stream>>>(
        heads_bf, Wt_o, b_o, out_output, nullptr, 0, L_Q, DIM, HDh);
}